// Round 1
// baseline (1212.816 us; speedup 1.0000x reference)
//
#include <hip/hip_runtime.h>
#include <math.h>

// PostEncode: graph-attention recsys forward.
// N=16384 nodes, L=50 history, E=64, CE=128.
// Strategy R1: f32 VALU baseline. Block=256thr (4 waves) per node; wave g owns
// rows (lb+g, lb+g+4); lane = output column e. 2 rows/thread so each weight
// load (L1/L2-resident, 96KB total) feeds 2 FMAs. Intermediates in LDS (~25KB
// -> ~6 blocks/CU). post@A1[64:128] hoisted per-node. Softmax+hist+Ow by wave0.

#define NN 16384
#define LL 50
#define EE 64

template <int K>
__device__ __forceinline__ void mm2(const float* row0, const float* row1,
                                    const float* __restrict__ W, int e,
                                    float& acc0, float& acc1)
{
  const float4* r0 = (const float4*)row0;
  const float4* r1 = (const float4*)row1;
#pragma unroll 4
  for (int k4 = 0; k4 < K / 4; ++k4) {
    float4 va = r0[k4];
    float4 vb = r1[k4];
    const float* w = W + (k4 * 4) * EE + e;
    float w0 = w[0], w1 = w[EE], w2 = w[2 * EE], w3 = w[3 * EE];
    acc0 = fmaf(va.x, w0, acc0);  acc1 = fmaf(vb.x, w0, acc1);
    acc0 = fmaf(va.y, w1, acc0);  acc1 = fmaf(vb.y, w1, acc1);
    acc0 = fmaf(va.z, w2, acc0);  acc1 = fmaf(vb.z, w2, acc1);
    acc0 = fmaf(va.w, w3, acc0);  acc1 = fmaf(vb.w, w3, acc1);
  }
}

__global__ __launch_bounds__(256, 4)
void postenc_kernel(
    const float* __restrict__ u2e, const float* __restrict__ r2e,
    const float* __restrict__ content_emb,
    const float* __restrict__ We_w, const float* __restrict__ We_b,
    const float* __restrict__ W1_w, const float* __restrict__ W1_b,
    const float* __restrict__ W2_w, const float* __restrict__ W2_b,
    const float* __restrict__ A1_w, const float* __restrict__ A1_b,
    const float* __restrict__ A2_w, const float* __restrict__ A2_b,
    const float* __restrict__ A3_w, const float* __restrict__ A3_b,
    const float* __restrict__ Ow_w, const float* __restrict__ Ow_b,
    const int* __restrict__ pu_history, const int* __restrict__ pr_history,
    const int* __restrict__ lengths, const int* __restrict__ pr_content,
    float* __restrict__ out)
{
  const int n = blockIdx.x;
  const int tid = (int)threadIdx.x;
  const int e = tid & 63;
  const int g = tid >> 6;

  __shared__ float post_s[EE];
  __shared__ float abase_s[EE];
  __shared__ float in_s[8][128];
  __shared__ float x_s[8][EE];
  __shared__ float a_s[8][EE];
  __shared__ float o_s[56][EE];
  __shared__ float logit_s[EE];
  __shared__ float att_s[EE];
  __shared__ float red_s[4][EE];

  const int len = lengths[n];
  float p = 0.f;  // this lane's post[e] (wave 0 only), reused in epilogue

  // ---- post = relu(content_emb[pr_content] @ We + b); abase = A1_b + post @ A1[64:128]
  if (g == 0) {
    const float* ce = content_emb + (size_t)pr_content[n] * 128;
    float acc = We_b[e];
#pragma unroll 4
    for (int k = 0; k < 128; ++k)
      acc = fmaf(ce[k], We_w[k * EE + e], acc);
    p = fmaxf(acc, 0.f);
    post_s[e] = p;
    float ab = A1_b[e];
#pragma unroll
    for (int k = 0; k < 64; ++k) {
      float pk = __shfl(p, k);
      ab = fmaf(pk, A1_w[(64 + k) * EE + e], ab);
    }
    abase_s[e] = ab;
    logit_s[e] = -INFINITY;
  }
  __syncthreads();

  // ---- main loop over history rows; wave g handles rows lb+g and lb+g+4
  for (int lb = 0; lb < 56; lb += 8) {
    const int l0 = lb + g;
    const int l1 = l0 + 4;
    const bool v0 = l0 < LL;
    const bool v1 = l1 < LL;

    int pu0 = 0, pr0 = 0, pu1 = 0, pr1 = 0;
    if (v0) { pu0 = pu_history[n * LL + l0]; pr0 = pr_history[n * LL + l0]; }
    if (v1) { pu1 = pu_history[n * LL + l1]; pr1 = pr_history[n * LL + l1]; }
    in_s[g][e]          = v0 ? u2e[(size_t)pu0 * EE + e] : 0.f;
    in_s[g][64 + e]     = v0 ? r2e[pr0 * EE + e]         : 0.f;
    in_s[g + 4][e]      = v1 ? u2e[(size_t)pu1 * EE + e] : 0.f;
    in_s[g + 4][64 + e] = v1 ? r2e[pr1 * EE + e]         : 0.f;
    __syncthreads();

    // x = relu([u;r] @ W1 + b1)
    float acc0 = W1_b[e], acc1 = acc0;
    mm2<128>(in_s[g], in_s[g + 4], W1_w, e, acc0, acc1);
    x_s[g][e]     = fmaxf(acc0, 0.f);
    x_s[g + 4][e] = fmaxf(acc1, 0.f);
    __syncthreads();

    // o = relu(x @ W2 + b2)
    acc0 = W2_b[e]; acc1 = acc0;
    mm2<64>(x_s[g], x_s[g + 4], W2_w, e, acc0, acc1);
    float o0 = fmaxf(acc0, 0.f);
    float o1 = fmaxf(acc1, 0.f);
    if (v0) o_s[l0][e] = o0;
    if (v1) o_s[l1][e] = o1;
    x_s[g][e]     = o0;  // reuse x_s as o-row staging for A1 input
    x_s[g + 4][e] = o1;
    __syncthreads();

    // a1 = relu([o;post] @ A1 + b) = relu(o @ A1[0:64] + abase)
    acc0 = abase_s[e]; acc1 = acc0;
    mm2<64>(x_s[g], x_s[g + 4], A1_w, e, acc0, acc1);
    a_s[g][e]     = fmaxf(acc0, 0.f);
    a_s[g + 4][e] = fmaxf(acc1, 0.f);
    __syncthreads();

    // a2 = relu(a1 @ A2 + b2); logit = a2 . A3 + A3_b
    acc0 = A2_b[e]; acc1 = acc0;
    mm2<64>(a_s[g], a_s[g + 4], A2_w, e, acc0, acc1);
    float w3 = A3_w[e];
    float p0 = fmaxf(acc0, 0.f) * w3;
    float p1 = fmaxf(acc1, 0.f) * w3;
#pragma unroll
    for (int off = 32; off > 0; off >>= 1) {
      p0 += __shfl_xor(p0, off);
      p1 += __shfl_xor(p1, off);
    }
    if (e == 0) {
      float b3 = A3_b[0];
      if (l0 < len) logit_s[l0] = p0 + b3;
      if (l1 < len) logit_s[l1] = p1 + b3;
    }
    __syncthreads();
  }

  // ---- masked softmax over L (wave 0); logit_s[l>=len] stayed -inf
  if (g == 0) {
    float lg = logit_s[e];
    float m = lg;
#pragma unroll
    for (int off = 32; off > 0; off >>= 1) m = fmaxf(m, __shfl_xor(m, off));
    float pe = __expf(lg - m);
    float s = pe;
#pragma unroll
    for (int off = 32; off > 0; off >>= 1) s += __shfl_xor(s, off);
    att_s[e] = pe / s;
  }
  __syncthreads();

  // ---- hist[e] = sum_l att[l] * o[l][e]  (4-way l-split across waves)
  {
    const int l_lo = 13 * g;
    const int l_hi = (13 * g + 13 < LL) ? 13 * g + 13 : LL;
    float h = 0.f;
    for (int l = l_lo; l < l_hi; ++l)
      h = fmaf(att_s[l], o_s[l][e], h);
    red_s[g][e] = h;
  }
  __syncthreads();

  // ---- out = relu([hist;post] @ Ow + b)  (wave 0, shuffle broadcasts)
  if (g == 0) {
    float h = red_s[0][e] + red_s[1][e] + red_s[2][e] + red_s[3][e];
    float acc = Ow_b[e];
#pragma unroll
    for (int k = 0; k < 64; ++k) {
      float hk = __shfl(h, k);
      acc = fmaf(hk, Ow_w[k * EE + e], acc);
    }
#pragma unroll
    for (int k = 0; k < 64; ++k) {
      float pk = __shfl(p, k);
      acc = fmaf(pk, Ow_w[(64 + k) * EE + e], acc);
    }
    out[(size_t)n * EE + e] = fmaxf(acc, 0.f);
  }
}

extern "C" void kernel_launch(void* const* d_in, const int* in_sizes, int n_in,
                              void* d_out, int out_size, void* d_ws, size_t ws_size,
                              hipStream_t stream) {
  const float* u2e         = (const float*)d_in[0];
  const float* r2e         = (const float*)d_in[1];
  const float* content_emb = (const float*)d_in[2];
  const float* We_w = (const float*)d_in[3];
  const float* We_b = (const float*)d_in[4];
  const float* W1_w = (const float*)d_in[5];
  const float* W1_b = (const float*)d_in[6];
  const float* W2_w = (const float*)d_in[7];
  const float* W2_b = (const float*)d_in[8];
  const float* A1_w = (const float*)d_in[9];
  const float* A1_b = (const float*)d_in[10];
  const float* A2_w = (const float*)d_in[11];
  const float* A2_b = (const float*)d_in[12];
  const float* A3_w = (const float*)d_in[13];
  const float* A3_b = (const float*)d_in[14];
  const float* Ow_w = (const float*)d_in[15];
  const float* Ow_b = (const float*)d_in[16];
  // d_in[17] = nodes (unused by the reference computation)
  const int* pu_history = (const int*)d_in[18];
  const int* pr_history = (const int*)d_in[19];
  const int* lengths    = (const int*)d_in[20];
  const int* pr_content = (const int*)d_in[21];
  float* out = (float*)d_out;

  postenc_kernel<<<NN, 256, 0, stream>>>(
      u2e, r2e, content_emb, We_w, We_b, W1_w, W1_b, W2_w, W2_b,
      A1_w, A1_b, A2_w, A2_b, A3_w, A3_b, Ow_w, Ow_b,
      pu_history, pr_history, lengths, pr_content, out);
}

// Round 2
// 205.348 us; speedup vs baseline: 5.9062x; 5.9062x over previous
//
#include <hip/hip_runtime.h>
#include <hip/hip_bf16.h>
#include <math.h>

// PostEncode R2: bf16-MFMA transposed-chain MLP.
// N=16384 nodes, L=50 history, E=64, CE=128.
//
// Pipeline (3 kernels, all on `stream`):
//  S2 setup_kernel: post[n]=relu(ce@We+b), abase[n]=A1_b+post@A1[64:]  (f32, ws)
//  A  mlp_kernel:   per 16-row tile (node n, rows 16*lt..+15, skipped if
//                   16*lt>=len): transposed chain X1^T=relu(W1^T X^T) ->
//                   o^T -> a1^T(+abase) -> a2^T -> logits. Weights live as
//                   bf16 A-frags in VGPRs; MFMA C/D output repacks IN-LANE
//                   into the next layer's B-frag via a chosen K-enumeration
//                   k(s,g,j)=32s+16(j>>2)+4g+(j&3) that matches the verified
//                   C/D layout (col=lane&15, row=(lane>>4)*4+reg). o rows and
//                   logits go to ws for kernel B.
//  B  attn_kernel:  per node: masked softmax over logits, hist=sum att*o,
//                   out=relu([hist;post]@Ow+b).
// Fallback: if ws_size < ~111MB, run the R1 all-f32 kernel.

#define NN 16384
#define LL 50
#define EE 64

typedef __attribute__((ext_vector_type(8))) short short8;
typedef __attribute__((ext_vector_type(4))) float f32x4;

static __device__ __forceinline__ unsigned short f2bf(float x) {
  __hip_bfloat16 h = __float2bfloat16(x);
  unsigned short u;
  __builtin_memcpy(&u, &h, 2);
  return u;
}

static __device__ __forceinline__ float bf2f(unsigned short u) {
  unsigned int v = ((unsigned int)u) << 16;
  float f;
  __builtin_memcpy(&f, &v, 4);
  return f;
}

static __device__ __forceinline__ f32x4 ld4(const float* p) {
  return *(const f32x4*)p;
}

static __device__ __forceinline__ f32x4 relu4(f32x4 a) {
  f32x4 r;
  r[0] = fmaxf(a[0], 0.f); r[1] = fmaxf(a[1], 0.f);
  r[2] = fmaxf(a[2], 0.f); r[3] = fmaxf(a[3], 0.f);
  return r;
}

static __device__ __forceinline__ short8 pack8(f32x4 a, f32x4 b) {
  short8 r;
  r[0] = (short)f2bf(a[0]); r[1] = (short)f2bf(a[1]);
  r[2] = (short)f2bf(a[2]); r[3] = (short)f2bf(a[3]);
  r[4] = (short)f2bf(b[0]); r[5] = (short)f2bf(b[1]);
  r[6] = (short)f2bf(b[2]); r[7] = (short)f2bf(b[3]);
  return r;
}

#define MFMA(A, B, C) __builtin_amdgcn_mfma_f32_16x16x32_bf16((A), (B), (C), 0, 0, 0)

// ---------------- S2: post + abase ----------------
__global__ __launch_bounds__(64)
void setup_kernel(const float* __restrict__ content_emb,
                  const int* __restrict__ pr_content,
                  const float* __restrict__ We_w, const float* __restrict__ We_b,
                  const float* __restrict__ A1_w, const float* __restrict__ A1_b,
                  float* __restrict__ post_ws, float* __restrict__ abase_ws) {
  const int n = blockIdx.x;
  const int e = threadIdx.x;
  __shared__ float ce_s[128];
  __shared__ float post_s[64];
  const float* ce = content_emb + (size_t)pr_content[n] * 128;
  ce_s[e] = ce[e];
  ce_s[64 + e] = ce[64 + e];
  __syncthreads();
  float acc = We_b[e];
#pragma unroll 8
  for (int k = 0; k < 128; ++k) acc = fmaf(ce_s[k], We_w[k * EE + e], acc);
  float po = fmaxf(acc, 0.f);
  post_s[e] = po;
  post_ws[n * EE + e] = po;
  __syncthreads();
  float ab = A1_b[e];
#pragma unroll 8
  for (int k = 0; k < 64; ++k) ab = fmaf(post_s[k], A1_w[(64 + k) * EE + e], ab);
  abase_ws[n * EE + e] = ab;
}

// ---------------- A: MFMA transposed-chain MLP ----------------
__global__ __launch_bounds__(256, 2)
void mlp_kernel(const float* __restrict__ u2e, const float* __restrict__ r2e,
                const float* __restrict__ W1_w, const float* __restrict__ W1_b,
                const float* __restrict__ W2_w, const float* __restrict__ W2_b,
                const float* __restrict__ A1_w,
                const float* __restrict__ A2_w, const float* __restrict__ A2_b,
                const float* __restrict__ A3_w, const float* __restrict__ A3_b,
                const int* __restrict__ pu_history, const int* __restrict__ pr_history,
                const int* __restrict__ lengths,
                const float* __restrict__ abase_ws,
                float* __restrict__ logits_ws, unsigned short* __restrict__ o_ws) {
  const int lane = (int)(threadIdx.x & 63u);
  const int g = lane >> 4;
  const int c = lane & 15;
  const int wave = blockIdx.x * (blockDim.x >> 6) + (threadIdx.x >> 6);
  const int nwaves = gridDim.x * (blockDim.x >> 6);

  // ---- build weight fragments (bf16) in VGPRs, once per wave ----
  // L1 (K=128): k_enum(s,g,j) = 32s + 8g + j   (matches Xf gather below)
  short8 Wf1[4][4];
#pragma unroll
  for (int mt = 0; mt < 4; ++mt)
#pragma unroll
    for (int s = 0; s < 4; ++s)
#pragma unroll
      for (int j = 0; j < 8; ++j)
        Wf1[mt][s][j] = (short)f2bf(W1_w[(32 * s + 8 * g + j) * EE + 16 * mt + c]);
  // L2..L4 (K=64): k_enum(s,g,j) = 32s + 16*(j>>2) + 4g + (j&3)
  // (chosen so that the previous layer's C/D output IS the B-frag in-lane)
  short8 Wf2[4][2], Wf3[4][2], Wf4[4][2];
#pragma unroll
  for (int mt = 0; mt < 4; ++mt)
#pragma unroll
    for (int s = 0; s < 2; ++s)
#pragma unroll
      for (int j = 0; j < 8; ++j) {
        const int k = 32 * s + 16 * (j >> 2) + 4 * g + (j & 3);
        Wf2[mt][s][j] = (short)f2bf(W2_w[k * EE + 16 * mt + c]);
        Wf3[mt][s][j] = (short)f2bf(A1_w[k * EE + 16 * mt + c]);
        Wf4[mt][s][j] = (short)f2bf(A2_w[k * EE + 16 * mt + c]);
      }

  const float b3 = A3_b[0];

  for (int tau = wave; tau < NN * 4; tau += nwaves) {
    const int n = tau >> 2;
    const int l0 = (tau & 3) << 4;
    const int len = lengths[n];
    if (l0 >= len) continue;

    const int t = l0 + c;           // this lane's data row within the node
    const bool vr = (t < LL);
    const int hidx = n * LL + (vr ? t : 0);
    const int pu = vr ? pu_history[hidx] : 0;
    const int pr = vr ? pr_history[hidx] : 0;

    // ---- gather X^T B-frags: row c = [u;r], k = 32s+8g+j ----
    const float* up = u2e + (size_t)pu * EE;
    const float* rp = r2e + (size_t)pr * EE;
    short8 Xf[4];
    Xf[0] = pack8(ld4(up + 8 * g), ld4(up + 8 * g + 4));
    Xf[1] = pack8(ld4(up + 32 + 8 * g), ld4(up + 32 + 8 * g + 4));
    Xf[2] = pack8(ld4(rp + 8 * g), ld4(rp + 8 * g + 4));
    Xf[3] = pack8(ld4(rp + 32 + 8 * g), ld4(rp + 32 + 8 * g + 4));

    // ---- L1: X1^T = relu(W1^T X^T + b1) ----
    f32x4 acc[4];
#pragma unroll
    for (int mt = 0; mt < 4; ++mt) acc[mt] = ld4(W1_b + 16 * mt + 4 * g);
#pragma unroll
    for (int s = 0; s < 4; ++s)
#pragma unroll
      for (int mt = 0; mt < 4; ++mt)
        acc[mt] = MFMA(Wf1[mt][s], Xf[s], acc[mt]);
#pragma unroll
    for (int mt = 0; mt < 4; ++mt) acc[mt] = relu4(acc[mt]);
    short8 Bf[2];
    Bf[0] = pack8(acc[0], acc[1]);
    Bf[1] = pack8(acc[2], acc[3]);

    // ---- L2: o^T = relu(W2^T X1^T + b2) ----
    f32x4 acc2[4];
#pragma unroll
    for (int mt = 0; mt < 4; ++mt) acc2[mt] = ld4(W2_b + 16 * mt + 4 * g);
#pragma unroll
    for (int s = 0; s < 2; ++s)
#pragma unroll
      for (int mt = 0; mt < 4; ++mt)
        acc2[mt] = MFMA(Wf2[mt][s], Bf[s], acc2[mt]);
#pragma unroll
    for (int mt = 0; mt < 4; ++mt) acc2[mt] = relu4(acc2[mt]);
    // store o rows (bf16) for kernel B: o[n*50+t][16mt+4g + 0..3]
    if (vr) {
      unsigned short* ob = o_ws + ((size_t)(n * LL + t)) * EE;
#pragma unroll
      for (int mt = 0; mt < 4; ++mt) {
        ushort4 ov;
        ov.x = f2bf(acc2[mt][0]); ov.y = f2bf(acc2[mt][1]);
        ov.z = f2bf(acc2[mt][2]); ov.w = f2bf(acc2[mt][3]);
        *reinterpret_cast<ushort4*>(ob + 16 * mt + 4 * g) = ov;
      }
    }
    Bf[0] = pack8(acc2[0], acc2[1]);
    Bf[1] = pack8(acc2[2], acc2[3]);

    // ---- L3: a1^T = relu(A1a^T o^T + abase[n]) ----
    f32x4 acc3[4];
#pragma unroll
    for (int mt = 0; mt < 4; ++mt) acc3[mt] = ld4(abase_ws + n * EE + 16 * mt + 4 * g);
#pragma unroll
    for (int s = 0; s < 2; ++s)
#pragma unroll
      for (int mt = 0; mt < 4; ++mt)
        acc3[mt] = MFMA(Wf3[mt][s], Bf[s], acc3[mt]);
#pragma unroll
    for (int mt = 0; mt < 4; ++mt) acc3[mt] = relu4(acc3[mt]);
    Bf[0] = pack8(acc3[0], acc3[1]);
    Bf[1] = pack8(acc3[2], acc3[3]);

    // ---- L4: a2^T = relu(A2^T a1^T + b) ; logits = a2 . A3 + b3 ----
    f32x4 acc4[4];
#pragma unroll
    for (int mt = 0; mt < 4; ++mt) acc4[mt] = ld4(A2_b + 16 * mt + 4 * g);
#pragma unroll
    for (int s = 0; s < 2; ++s)
#pragma unroll
      for (int mt = 0; mt < 4; ++mt)
        acc4[mt] = MFMA(Wf4[mt][s], Bf[s], acc4[mt]);

    float part = 0.f;
#pragma unroll
    for (int mt = 0; mt < 4; ++mt) {
      f32x4 a3 = ld4(A3_w + 16 * mt + 4 * g);
      f32x4 r = relu4(acc4[mt]);
      part = fmaf(r[0], a3[0], part);
      part = fmaf(r[1], a3[1], part);
      part = fmaf(r[2], a3[2], part);
      part = fmaf(r[3], a3[3], part);
    }
    part += __shfl_xor(part, 16);
    part += __shfl_xor(part, 32);
    if (g == 0 && vr) logits_ws[n * LL + t] = part + b3;
  }
}

// ---------------- B: softmax + hist + output projection ----------------
__global__ __launch_bounds__(64)
void attn_kernel(const float* __restrict__ logits_ws,
                 const unsigned short* __restrict__ o_ws,
                 const float* __restrict__ post_ws,
                 const float* __restrict__ Ow_w, const float* __restrict__ Ow_b,
                 const int* __restrict__ lengths,
                 float* __restrict__ out) {
  const int n = blockIdx.x;
  const int e = (int)threadIdx.x;  // 64 threads = 1 wave
  const int len = lengths[n];

  float lg = (e < len) ? logits_ws[n * LL + e] : -INFINITY;
  float m = lg;
#pragma unroll
  for (int off = 32; off > 0; off >>= 1) m = fmaxf(m, __shfl_xor(m, off));
  float p = __expf(lg - m);  // -inf -> 0
  float s = p;
#pragma unroll
  for (int off = 32; off > 0; off >>= 1) s += __shfl_xor(s, off);
  const float att = p / s;

  float hist = 0.f;
  const unsigned short* ob = o_ws + (size_t)n * LL * EE + e;
  for (int l = 0; l < len; ++l) {
    float a = __shfl(att, l);
    hist = fmaf(a, bf2f(ob[l * EE]), hist);
  }

  const float po = post_ws[n * EE + e];
  float acc = Ow_b[e];
#pragma unroll 8
  for (int k = 0; k < 64; ++k)
    acc = fmaf(__shfl(hist, k), Ow_w[k * EE + e], acc);
#pragma unroll 8
  for (int k = 0; k < 64; ++k)
    acc = fmaf(__shfl(po, k), Ow_w[(64 + k) * EE + e], acc);
  out[(size_t)n * EE + e] = fmaxf(acc, 0.f);
}

// ---------------- R1 fallback (all-f32, no workspace) ----------------
template <int K>
__device__ __forceinline__ void mm2(const float* row0, const float* row1,
                                    const float* __restrict__ W, int e,
                                    float& acc0, float& acc1) {
  const float4* r0 = (const float4*)row0;
  const float4* r1 = (const float4*)row1;
#pragma unroll 4
  for (int k4 = 0; k4 < K / 4; ++k4) {
    float4 va = r0[k4];
    float4 vb = r1[k4];
    const float* w = W + (k4 * 4) * EE + e;
    float w0 = w[0], w1 = w[EE], w2 = w[2 * EE], w3 = w[3 * EE];
    acc0 = fmaf(va.x, w0, acc0);  acc1 = fmaf(vb.x, w0, acc1);
    acc0 = fmaf(va.y, w1, acc0);  acc1 = fmaf(vb.y, w1, acc1);
    acc0 = fmaf(va.z, w2, acc0);  acc1 = fmaf(vb.z, w2, acc1);
    acc0 = fmaf(va.w, w3, acc0);  acc1 = fmaf(vb.w, w3, acc1);
  }
}

__global__ __launch_bounds__(256, 4)
void postenc_kernel(
    const float* __restrict__ u2e, const float* __restrict__ r2e,
    const float* __restrict__ content_emb,
    const float* __restrict__ We_w, const float* __restrict__ We_b,
    const float* __restrict__ W1_w, const float* __restrict__ W1_b,
    const float* __restrict__ W2_w, const float* __restrict__ W2_b,
    const float* __restrict__ A1_w, const float* __restrict__ A1_b,
    const float* __restrict__ A2_w, const float* __restrict__ A2_b,
    const float* __restrict__ A3_w, const float* __restrict__ A3_b,
    const float* __restrict__ Ow_w, const float* __restrict__ Ow_b,
    const int* __restrict__ pu_history, const int* __restrict__ pr_history,
    const int* __restrict__ lengths, const int* __restrict__ pr_content,
    float* __restrict__ out) {
  const int n = blockIdx.x;
  const int tid = (int)threadIdx.x;
  const int e = tid & 63;
  const int g = tid >> 6;

  __shared__ float post_s[EE];
  __shared__ float abase_s[EE];
  __shared__ float in_s[8][128];
  __shared__ float x_s[8][EE];
  __shared__ float a_s[8][EE];
  __shared__ float o_s[56][EE];
  __shared__ float logit_s[EE];
  __shared__ float att_s[EE];
  __shared__ float red_s[4][EE];

  const int len = lengths[n];
  float p = 0.f;

  if (g == 0) {
    const float* ce = content_emb + (size_t)pr_content[n] * 128;
    float acc = We_b[e];
#pragma unroll 4
    for (int k = 0; k < 128; ++k) acc = fmaf(ce[k], We_w[k * EE + e], acc);
    p = fmaxf(acc, 0.f);
    post_s[e] = p;
    float ab = A1_b[e];
#pragma unroll
    for (int k = 0; k < 64; ++k) {
      float pk = __shfl(p, k);
      ab = fmaf(pk, A1_w[(64 + k) * EE + e], ab);
    }
    abase_s[e] = ab;
    logit_s[e] = -INFINITY;
  }
  __syncthreads();

  for (int lb = 0; lb < 56; lb += 8) {
    const int l0 = lb + g;
    const int l1 = l0 + 4;
    const bool v0 = l0 < LL;
    const bool v1 = l1 < LL;

    int pu0 = 0, pr0 = 0, pu1 = 0, pr1 = 0;
    if (v0) { pu0 = pu_history[n * LL + l0]; pr0 = pr_history[n * LL + l0]; }
    if (v1) { pu1 = pu_history[n * LL + l1]; pr1 = pr_history[n * LL + l1]; }
    in_s[g][e]          = v0 ? u2e[(size_t)pu0 * EE + e] : 0.f;
    in_s[g][64 + e]     = v0 ? r2e[pr0 * EE + e]         : 0.f;
    in_s[g + 4][e]      = v1 ? u2e[(size_t)pu1 * EE + e] : 0.f;
    in_s[g + 4][64 + e] = v1 ? r2e[pr1 * EE + e]         : 0.f;
    __syncthreads();

    float acc0 = W1_b[e], acc1 = acc0;
    mm2<128>(in_s[g], in_s[g + 4], W1_w, e, acc0, acc1);
    x_s[g][e]     = fmaxf(acc0, 0.f);
    x_s[g + 4][e] = fmaxf(acc1, 0.f);
    __syncthreads();

    acc0 = W2_b[e]; acc1 = acc0;
    mm2<64>(x_s[g], x_s[g + 4], W2_w, e, acc0, acc1);
    float o0 = fmaxf(acc0, 0.f);
    float o1 = fmaxf(acc1, 0.f);
    if (v0) o_s[l0][e] = o0;
    if (v1) o_s[l1][e] = o1;
    x_s[g][e]     = o0;
    x_s[g + 4][e] = o1;
    __syncthreads();

    acc0 = abase_s[e]; acc1 = acc0;
    mm2<64>(x_s[g], x_s[g + 4], A1_w, e, acc0, acc1);
    a_s[g][e]     = fmaxf(acc0, 0.f);
    a_s[g + 4][e] = fmaxf(acc1, 0.f);
    __syncthreads();

    acc0 = A2_b[e]; acc1 = acc0;
    mm2<64>(a_s[g], a_s[g + 4], A2_w, e, acc0, acc1);
    float w3 = A3_w[e];
    float p0 = fmaxf(acc0, 0.f) * w3;
    float p1 = fmaxf(acc1, 0.f) * w3;
#pragma unroll
    for (int off = 32; off > 0; off >>= 1) {
      p0 += __shfl_xor(p0, off);
      p1 += __shfl_xor(p1, off);
    }
    if (e == 0) {
      float b3 = A3_b[0];
      if (l0 < len) logit_s[l0] = p0 + b3;
      if (l1 < len) logit_s[l1] = p1 + b3;
    }
    __syncthreads();
  }

  if (g == 0) {
    float lg = logit_s[e];
    float m = lg;
#pragma unroll
    for (int off = 32; off > 0; off >>= 1) m = fmaxf(m, __shfl_xor(m, off));
    float pe = __expf(lg - m);
    float sm = pe;
#pragma unroll
    for (int off = 32; off > 0; off >>= 1) sm += __shfl_xor(sm, off);
    att_s[e] = pe / sm;
  }
  __syncthreads();

  {
    const int l_lo = 13 * g;
    const int l_hi = (13 * g + 13 < LL) ? 13 * g + 13 : LL;
    float h = 0.f;
    for (int l = l_lo; l < l_hi; ++l) h = fmaf(att_s[l], o_s[l][e], h);
    red_s[g][e] = h;
  }
  __syncthreads();

  if (g == 0) {
    float h = red_s[0][e] + red_s[1][e] + red_s[2][e] + red_s[3][e];
    float acc = Ow_b[e];
#pragma unroll
    for (int k = 0; k < 64; ++k) {
      float hk = __shfl(h, k);
      acc = fmaf(hk, Ow_w[k * EE + e], acc);
    }
#pragma unroll
    for (int k = 0; k < 64; ++k) {
      float pk = __shfl(p, k);
      acc = fmaf(pk, Ow_w[(64 + k) * EE + e], acc);
    }
    out[(size_t)n * EE + e] = fmaxf(acc, 0.f);
  }
}

// ---------------- launcher ----------------
extern "C" void kernel_launch(void* const* d_in, const int* in_sizes, int n_in,
                              void* d_out, int out_size, void* d_ws, size_t ws_size,
                              hipStream_t stream) {
  const float* u2e         = (const float*)d_in[0];
  const float* r2e         = (const float*)d_in[1];
  const float* content_emb = (const float*)d_in[2];
  const float* We_w = (const float*)d_in[3];
  const float* We_b = (const float*)d_in[4];
  const float* W1_w = (const float*)d_in[5];
  const float* W1_b = (const float*)d_in[6];
  const float* W2_w = (const float*)d_in[7];
  const float* W2_b = (const float*)d_in[8];
  const float* A1_w = (const float*)d_in[9];
  const float* A1_b = (const float*)d_in[10];
  const float* A2_w = (const float*)d_in[11];
  const float* A2_b = (const float*)d_in[12];
  const float* A3_w = (const float*)d_in[13];
  const float* A3_b = (const float*)d_in[14];
  const float* Ow_w = (const float*)d_in[15];
  const float* Ow_b = (const float*)d_in[16];
  // d_in[17] = nodes (unused)
  const int* pu_history = (const int*)d_in[18];
  const int* pr_history = (const int*)d_in[19];
  const int* lengths    = (const int*)d_in[20];
  const int* pr_content = (const int*)d_in[21];
  float* out = (float*)d_out;

  // workspace layout (bytes)
  const size_t O_OFF   = 0;                               // o bf16 [N*50][64]
  const size_t LG_OFF  = (size_t)NN * LL * EE * 2;        // 104857600
  const size_t PO_OFF  = LG_OFF + (size_t)NN * LL * 4;    // +3276800
  const size_t AB_OFF  = PO_OFF + (size_t)NN * EE * 4;    // +4194304
  const size_t NEED    = AB_OFF + (size_t)NN * EE * 4;    // 116523008

  if (ws_size < NEED) {
    postenc_kernel<<<NN, 256, 0, stream>>>(
        u2e, r2e, content_emb, We_w, We_b, W1_w, W1_b, W2_w, W2_b,
        A1_w, A1_b, A2_w, A2_b, A3_w, A3_b, Ow_w, Ow_b,
        pu_history, pr_history, lengths, pr_content, out);
    return;
  }

  char* w = (char*)d_ws;
  unsigned short* o_ws  = (unsigned short*)(w + O_OFF);
  float* logits_ws      = (float*)(w + LG_OFF);
  float* post_ws        = (float*)(w + PO_OFF);
  float* abase_ws       = (float*)(w + AB_OFF);

  setup_kernel<<<NN, 64, 0, stream>>>(content_emb, pr_content, We_w, We_b,
                                      A1_w, A1_b, post_ws, abase_ws);
  mlp_kernel<<<512, 256, 0, stream>>>(u2e, r2e, W1_w, W1_b, W2_w, W2_b,
                                      A1_w, A2_w, A2_b, A3_w, A3_b,
                                      pu_history, pr_history, lengths,
                                      abase_ws, logits_ws, o_ws);
  attn_kernel<<<NN, 64, 0, stream>>>(logits_ws, o_ws, post_ws, Ow_w, Ow_b,
                                     lengths, out);
}